// Round 1
// baseline (1042.699 us; speedup 1.0000x reference)
//
#include <hip/hip_runtime.h>
#include <math.h>

#define NN 4096   // nodes

// ---------------- adjacency -> bitmask (1 bit per edge) ----------------
__global__ void pack_adj_kernel(const int* __restrict__ adj,
                                unsigned long long* __restrict__ bits) {
    int gw = (blockIdx.x * blockDim.x + threadIdx.x) >> 6;   // word index: row*64 + wordcol
    int lane = threadIdx.x & 63;
    int v = adj[(size_t)gw * 64 + lane];
    unsigned long long m = __ballot(v > 0);
    if (lane == 0) bits[gw] = m;
}

// ---------------- prepack W_h [4,512,128] -> Bp [512,512] (k-major, col=h*128+f) ----
__global__ void prepack_kernel(const float* __restrict__ W_h, const float* __restrict__ b_h,
                               float* __restrict__ Bp, float* __restrict__ biasp) {
    int idx = blockIdx.x * 256 + threadIdx.x;
    if (idx < 512 * 512) {
        int k = idx >> 9, c = idx & 511;
        int h = c >> 7, f = c & 127;
        Bp[idx] = W_h[h * (512 * 128) + k * 128 + f];
    }
    if (idx < 512) biasp[idx] = b_h[idx];   // b_h flat [4*128] == col layout h*128+f
}

// ---------------- fp32 tiled SGEMM, C = A@B + bias ----------------
// BM=BN=64, BK=16, 256 threads, 4x4 micro-tile
__global__ __launch_bounds__(256) void sgemm_bias_kernel(
    const float* __restrict__ A, const float* __restrict__ B,
    const float* __restrict__ bias, float* __restrict__ C,
    int M, int N, int K)
{
    __shared__ float As[64][20];   // padded to 80B rows (16B-aligned float4 stores)
    __shared__ float Bs[16][64];
    const int tid = threadIdx.x;
    const int tx = tid & 15, ty = tid >> 4;
    const int bm = blockIdx.y * 64, bn = blockIdx.x * 64;
    const int ar = tid >> 2;            // 0..63
    const int ac = (tid & 3) * 4;       // 0,4,8,12
    const int br = tid >> 4;            // 0..15
    const int bc = (tid & 15) * 4;      // 0..60
    float acc[4][4] = {{0.f}};
    for (int k0 = 0; k0 < K; k0 += 16) {
        __syncthreads();
        float4 av = *(const float4*)(A + (size_t)(bm + ar) * K + k0 + ac);
        *(float4*)(&As[ar][ac]) = av;
        float4 bv = *(const float4*)(B + (size_t)(k0 + br) * N + bn + bc);
        *(float4*)(&Bs[br][bc]) = bv;
        __syncthreads();
#pragma unroll
        for (int k = 0; k < 16; k++) {
            float b0 = Bs[k][tx * 4 + 0], b1 = Bs[k][tx * 4 + 1];
            float b2 = Bs[k][tx * 4 + 2], b3 = Bs[k][tx * 4 + 3];
#pragma unroll
            for (int i = 0; i < 4; i++) {
                float a = As[ty * 4 + i][k];
                acc[i][0] += a * b0; acc[i][1] += a * b1;
                acc[i][2] += a * b2; acc[i][3] += a * b3;
            }
        }
    }
#pragma unroll
    for (int i = 0; i < 4; i++) {
        float4 outv;
        outv.x = acc[i][0] + bias[bn + tx * 4 + 0];
        outv.y = acc[i][1] + bias[bn + tx * 4 + 1];
        outv.z = acc[i][2] + bias[bn + tx * 4 + 2];
        outv.w = acc[i][3] + bias[bn + tx * 4 + 3];
        *(float4*)(C + (size_t)(bm + ty * 4 + i) * N + bn + tx * 4) = outv;
    }
}

// ---------------- per-row logits s1 = h@a1 + ab, s2 = h@a2 ----------------
template<int FH>
__global__ void s12_kernel(const float* __restrict__ hfeat, int ldh, int heads,
                           const float* __restrict__ a1, const float* __restrict__ a2,
                           const float* __restrict__ ab,
                           float* __restrict__ s1, float* __restrict__ s2)
{
    int gw = (blockIdx.x * blockDim.x + threadIdx.x) >> 6;   // one wave per (row, head)
    int lane = threadIdx.x & 63;
    int row = gw / heads;
    int head = gw - row * heads;
    if (row >= NN) return;
    constexpr int E = FH / 64;
    const float* hr = hfeat + (size_t)row * ldh + head * FH;
    const float* a1h = a1 + head * FH;
    const float* a2h = a2 + head * FH;
    float p1 = 0.f, p2 = 0.f;
#pragma unroll
    for (int e = 0; e < E; e++) {
        float v = hr[lane * E + e];
        p1 += v * a1h[lane * E + e];
        p2 += v * a2h[lane * E + e];
    }
#pragma unroll
    for (int off = 1; off < 64; off <<= 1) {
        p1 += __shfl_xor(p1, off, 64);
        p2 += __shfl_xor(p2, off, 64);
    }
    if (lane == 0) {
        s1[head * NN + row] = p1 + ab[head];
        s2[head * NN + row] = p2;
    }
}

// ---------------- fused masked-softmax attention (flash-style) ----------------
// out[row, :] = elu( softmax_j( mask( lrelu(s1[i]+s2[j]) ) ) @ h )
// 16 rows/block, 64-col j-tiles, 16 lanes per row, FH/16 features per lane.
template<int FH>
__global__ __launch_bounds__(256) void attn_kernel(
    const float* __restrict__ hfeat, int ldh,
    const unsigned long long* __restrict__ adj_bits,
    const float* __restrict__ s1_all, const float* __restrict__ s2_all,
    float* __restrict__ outp, int ldo)
{
    constexpr int ROWS = 16;
    constexpr int FPL = FH / 16;
    constexpr int NF4 = FH / 4;
    const int head = blockIdx.y;
    const int row0 = blockIdx.x * ROWS;
    const int tid = threadIdx.x;
    const int wid = tid >> 6;
    const int lane = tid & 63;
    const int rlocal = (wid << 2) | (lane >> 4);   // 0..15, row-group fully inside one wave
    const int lr = lane & 15;
    const int row = row0 + rlocal;
    const int colOff = head * FH;
    const float* s1 = s1_all + head * NN;
    const float* s2 = s2_all + head * NN;

    __shared__ float htile[64][FH];
    __shared__ float s2tile[64];
    __shared__ float pbuf[ROWS][64];

    float acc[FPL];
#pragma unroll
    for (int f = 0; f < FPL; f++) acc[f] = 0.f;
    float mrow = -INFINITY, lrow = 0.f;
    const float s1r = s1[row];
    const int f0 = lr * FPL;
    const unsigned long long* mwp = adj_bits + (size_t)row * 64;

    for (int jt = 0; jt < NN / 64; jt++) {
        __syncthreads();
        for (int idx = tid; idx < 64 * NF4; idx += 256) {
            int jr = idx / NF4, c4 = idx - jr * NF4;
            *(float4*)(&htile[jr][c4 * 4]) =
                *(const float4*)(hfeat + (size_t)(jt * 64 + jr) * ldh + colOff + c4 * 4);
        }
        if (tid < 64) s2tile[tid] = s2[jt * 64 + tid];
        __syncthreads();

        unsigned long long mword = mwp[jt];
        float e[4], p[4];
        float tmax = -INFINITY;
#pragma unroll
        for (int q = 0; q < 4; q++) {
            int j = lr * 4 + q;
            float x = s1r + s2tile[j];
            x = x > 0.f ? x : 0.2f * x;               // leaky_relu(0.2)
            e[q] = ((mword >> j) & 1ULL) ? x : -INFINITY;
            tmax = fmaxf(tmax, e[q]);
        }
#pragma unroll
        for (int off = 1; off < 16; off <<= 1)
            tmax = fmaxf(tmax, __shfl_xor(tmax, off, 64));
        float mnew = fmaxf(mrow, tmax);
        float alpha;
        float psum = 0.f;
        if (mnew == -INFINITY) {                      // tile & history fully masked
            alpha = 1.f;
            p[0] = p[1] = p[2] = p[3] = 0.f;
        } else {
            alpha = __expf(mrow - mnew);              // mrow=-inf -> 0
#pragma unroll
            for (int q = 0; q < 4; q++) {
                p[q] = (e[q] == -INFINITY) ? 0.f : __expf(e[q] - mnew);
                psum += p[q];
            }
        }
#pragma unroll
        for (int off = 1; off < 16; off <<= 1)
            psum += __shfl_xor(psum, off, 64);
        lrow = lrow * alpha + psum;
        mrow = mnew;
        *(float4*)(&pbuf[rlocal][lr * 4]) = make_float4(p[0], p[1], p[2], p[3]);
#pragma unroll
        for (int f = 0; f < FPL; f++) acc[f] *= alpha;
        // intra-wave LDS write->read (same row-group, same wave): HW DS queue is in-order
#pragma unroll 2
        for (int j4 = 0; j4 < 16; j4++) {
            float4 pv = *(const float4*)(&pbuf[rlocal][j4 * 4]);
            float pj[4] = {pv.x, pv.y, pv.z, pv.w};
#pragma unroll
            for (int q = 0; q < 4; q++) {
                int jj = j4 * 4 + q;
#pragma unroll
                for (int f = 0; f < FPL; f++)
                    acc[f] += pj[q] * htile[jj][f0 + f];
            }
        }
    }
    float inv = 1.f / (lrow > 0.f ? lrow : 1.f);
    float* op = outp + (size_t)row * ldo + colOff + f0;
#pragma unroll
    for (int f = 0; f < FPL; f += 4) {
        float4 v; float x;
        x = acc[f + 0] * inv; v.x = x > 0.f ? x : __expf(x) - 1.f;   // elu
        x = acc[f + 1] * inv; v.y = x > 0.f ? x : __expf(x) - 1.f;
        x = acc[f + 2] * inv; v.z = x > 0.f ? x : __expf(x) - 1.f;
        x = acc[f + 3] * inv; v.w = x > 0.f ? x : __expf(x) - 1.f;
        *(float4*)(op + f) = v;
    }
}

// ---------------- row-wise log_softmax over 64 features ----------------
__global__ void logsoftmax_kernel(const float* __restrict__ in, float* __restrict__ out) {
    int gw = (blockIdx.x * blockDim.x + threadIdx.x) >> 6;   // one wave per row
    int lane = threadIdx.x & 63;
    if (gw >= NN) return;
    float v = in[(size_t)gw * 64 + lane];
    float m = v;
#pragma unroll
    for (int off = 1; off < 64; off <<= 1) m = fmaxf(m, __shfl_xor(m, off, 64));
    float ex = __expf(v - m);
    float s = ex;
#pragma unroll
    for (int off = 1; off < 64; off <<= 1) s += __shfl_xor(s, off, 64);
    out[(size_t)gw * 64 + lane] = v - m - __logf(s);
}

extern "C" void kernel_launch(void* const* d_in, const int* in_sizes, int n_in,
                              void* d_out, int out_size, void* d_ws, size_t ws_size,
                              hipStream_t stream) {
    const float* X    = (const float*)d_in[0];
    const int*   adj  = (const int*)d_in[1];
    const float* W_h  = (const float*)d_in[2];
    const float* b_h  = (const float*)d_in[3];
    const float* a1_h = (const float*)d_in[4];
    const float* a2_h = (const float*)d_in[5];
    const float* ab_h = (const float*)d_in[6];
    const float* W_o  = (const float*)d_in[7];
    const float* b_o  = (const float*)d_in[8];
    const float* a1_o = (const float*)d_in[9];
    const float* a2_o = (const float*)d_in[10];
    const float* ab_o = (const float*)d_in[11];
    float* out = (float*)d_out;

    char* ws = (char*)d_ws;
    auto alloc = [&](size_t bytes) {
        char* p = ws; ws += (bytes + 255) & ~(size_t)255; return p;
    };
    unsigned long long* adj_bits = (unsigned long long*)alloc((size_t)NN * 64 * 8); // 2 MB
    float* Bp    = (float*)alloc((size_t)512 * 512 * 4);   // 1 MB
    float* biasp = (float*)alloc(512 * 4);
    float* h_all = (float*)alloc((size_t)NN * 512 * 4);    // 8 MB
    float* s1h   = (float*)alloc(4 * NN * 4);
    float* s2h   = (float*)alloc(4 * NN * 4);
    float* outh  = (float*)alloc((size_t)NN * 512 * 4);    // 8 MB
    float* h2    = (float*)alloc((size_t)NN * 64 * 4);     // 1 MB
    float* s1o   = (float*)alloc(NN * 4);
    float* s2o   = (float*)alloc(NN * 4);
    float* out2  = (float*)alloc((size_t)NN * 64 * 4);     // 1 MB  (total ~22.3 MB)

    // 1. adjacency -> bitmasks (one read of the 67 MB int32 matrix)
    pack_adj_kernel<<<(NN * 64) / 4, 256, 0, stream>>>(adj, adj_bits);
    // 2. prepack head weights into one [512,512] B matrix
    prepack_kernel<<<1024, 256, 0, stream>>>(W_h, b_h, Bp, biasp);
    // 3. h_all[N,512] = X @ Bp + bias  (4 heads fused, col = h*128+f)
    sgemm_bias_kernel<<<dim3(8, 64), 256, 0, stream>>>(X, Bp, biasp, h_all, NN, 512, 512);
    // 4. per-row logit halves for 4 heads
    s12_kernel<128><<<4096, 256, 0, stream>>>(h_all, 512, 4, a1_h, a2_h, ab_h, s1h, s2h);
    // 5. fused masked-softmax attention + elu, all 4 heads -> outh[N,512] (concat layout)
    attn_kernel<128><<<dim3(NN / 16, 4), 256, 0, stream>>>(h_all, 512, adj_bits, s1h, s2h, outh, 512);
    // 6. output layer GEMM: h2[N,64] = outh @ W_o + b_o
    sgemm_bias_kernel<<<dim3(1, 64), 256, 0, stream>>>(outh, W_o, b_o, h2, NN, 64, 512);
    // 7. output layer logits
    s12_kernel<64><<<1024, 256, 0, stream>>>(h2, 64, 1, a1_o, a2_o, ab_o, s1o, s2o);
    // 8. output layer attention + elu
    attn_kernel<64><<<dim3(NN / 16, 1), 256, 0, stream>>>(h2, 64, adj_bits, s1o, s2o, out2, 64);
    // 9. log_softmax over the 64 features
    logsoftmax_kernel<<<1024, 256, 0, stream>>>(out2, out);
}

// Round 2
// 365.647 us; speedup vs baseline: 2.8517x; 2.8517x over previous
//
#include <hip/hip_runtime.h>
#include <math.h>

#define NN 4096   // nodes

using f32x4  = __attribute__((ext_vector_type(4))) float;
using bf16x8 = __attribute__((ext_vector_type(8))) __bf16;

// ---------------- adjacency -> bitmask (1 bit per edge) ----------------
__global__ void pack_adj_kernel(const int* __restrict__ adj,
                                unsigned long long* __restrict__ bits) {
    int gw = (blockIdx.x * blockDim.x + threadIdx.x) >> 6;   // word index: row*64 + wordcol
    int lane = threadIdx.x & 63;
    int v = adj[(size_t)gw * 64 + lane];
    unsigned long long m = __ballot(v > 0);
    if (lane == 0) bits[gw] = m;
}

// ---------------- prepack W_h [4,512,128] -> Bp [512,512] (k-major, col=h*128+f) ----
__global__ void prepack_kernel(const float* __restrict__ W_h, const float* __restrict__ b_h,
                               float* __restrict__ Bp, float* __restrict__ biasp) {
    int idx = blockIdx.x * 256 + threadIdx.x;
    if (idx < 512 * 512) {
        int k = idx >> 9, c = idx & 511;
        int h = c >> 7, f = c & 127;
        Bp[idx] = W_h[h * (512 * 128) + k * 128 + f];
    }
    if (idx < 512) biasp[idx] = b_h[idx];
}

// ---------------- fp32 tiled SGEMM, C = A@B + bias ----------------
__global__ __launch_bounds__(256) void sgemm_bias_kernel(
    const float* __restrict__ A, const float* __restrict__ B,
    const float* __restrict__ bias, float* __restrict__ C,
    int M, int N, int K)
{
    __shared__ float As[64][20];
    __shared__ float Bs[16][64];
    const int tid = threadIdx.x;
    const int tx = tid & 15, ty = tid >> 4;
    const int bm = blockIdx.y * 64, bn = blockIdx.x * 64;
    const int ar = tid >> 2;
    const int ac = (tid & 3) * 4;
    const int br = tid >> 4;
    const int bc = (tid & 15) * 4;
    float acc[4][4] = {{0.f}};
    for (int k0 = 0; k0 < K; k0 += 16) {
        __syncthreads();
        float4 av = *(const float4*)(A + (size_t)(bm + ar) * K + k0 + ac);
        *(float4*)(&As[ar][ac]) = av;
        float4 bv = *(const float4*)(B + (size_t)(k0 + br) * N + bn + bc);
        *(float4*)(&Bs[br][bc]) = bv;
        __syncthreads();
#pragma unroll
        for (int k = 0; k < 16; k++) {
            float b0 = Bs[k][tx * 4 + 0], b1 = Bs[k][tx * 4 + 1];
            float b2 = Bs[k][tx * 4 + 2], b3 = Bs[k][tx * 4 + 3];
#pragma unroll
            for (int i = 0; i < 4; i++) {
                float a = As[ty * 4 + i][k];
                acc[i][0] += a * b0; acc[i][1] += a * b1;
                acc[i][2] += a * b2; acc[i][3] += a * b3;
            }
        }
    }
#pragma unroll
    for (int i = 0; i < 4; i++) {
        float4 outv;
        outv.x = acc[i][0] + bias[bn + tx * 4 + 0];
        outv.y = acc[i][1] + bias[bn + tx * 4 + 1];
        outv.z = acc[i][2] + bias[bn + tx * 4 + 2];
        outv.w = acc[i][3] + bias[bn + tx * 4 + 3];
        *(float4*)(C + (size_t)(bm + ty * 4 + i) * N + bn + tx * 4) = outv;
    }
}

// ---------------- per-row logits s1 = h@a1 + ab, s2 = h@a2 ----------------
template<int FH>
__global__ void s12_kernel(const float* __restrict__ hfeat, int ldh, int heads,
                           const float* __restrict__ a1, const float* __restrict__ a2,
                           const float* __restrict__ ab,
                           float* __restrict__ s1, float* __restrict__ s2)
{
    int gw = (blockIdx.x * blockDim.x + threadIdx.x) >> 6;
    int lane = threadIdx.x & 63;
    int row = gw / heads;
    int head = gw - row * heads;
    if (row >= NN) return;
    constexpr int E = FH / 64;
    const float* hr = hfeat + (size_t)row * ldh + head * FH;
    const float* a1h = a1 + head * FH;
    const float* a2h = a2 + head * FH;
    float p1 = 0.f, p2 = 0.f;
#pragma unroll
    for (int e = 0; e < E; e++) {
        float v = hr[lane * E + e];
        p1 += v * a1h[lane * E + e];
        p2 += v * a2h[lane * E + e];
    }
#pragma unroll
    for (int off = 1; off < 64; off <<= 1) {
        p1 += __shfl_xor(p1, off, 64);
        p2 += __shfl_xor(p2, off, 64);
    }
    if (lane == 0) {
        s1[head * NN + row] = p1 + ab[head];
        s2[head * NN + row] = p2;
    }
}

// ---------------- global max of s2 per head (upper bound for softmax) ----------------
__global__ void smax_kernel(const float* __restrict__ s2, float* __restrict__ s2max) {
    const float* p = s2 + (size_t)blockIdx.x * NN;
    int t = threadIdx.x;
    float m = -INFINITY;
    for (int i = t; i < NN; i += 256) m = fmaxf(m, p[i]);
#pragma unroll
    for (int off = 1; off < 64; off <<= 1) m = fmaxf(m, __shfl_xor(m, off, 64));
    __shared__ float red[4];
    if ((t & 63) == 0) red[t >> 6] = m;
    __syncthreads();
    if (t == 0) s2max[blockIdx.x] = fmaxf(fmaxf(red[0], red[1]), fmaxf(red[2], red[3]));
}

// ---------------- transpose + fp32->bf16: src[R][C] -> dst[C][R] ----------------
__global__ __launch_bounds__(256) void transpose_cvt_kernel(
    const float* __restrict__ src, __bf16* __restrict__ dst, int R, int C)
{
    __shared__ float tile[32][33];
    int tx = threadIdx.x & 31, ty = threadIdx.x >> 5;
    int c0 = blockIdx.x * 32, r0 = blockIdx.y * 32;
#pragma unroll
    for (int i = 0; i < 4; i++)
        tile[ty + 8 * i][tx] = src[(size_t)(r0 + ty + 8 * i) * C + c0 + tx];
    __syncthreads();
#pragma unroll
    for (int i = 0; i < 4; i++)
        dst[(size_t)(c0 + ty + 8 * i) * R + r0 + tx] = (__bf16)tile[tx][ty + 8 * i];
}

// ---------------- MFMA fused masked-softmax attention ----------------
// out[row,:] = elu( softmax_j( mask( lrelu(s1[i]+s2[j]) ) ) @ h )
// Logits are rank-1, so the only GEMM is P@H (bf16 MFMA 16x16x32).
// m_i = lrelu(s1_i + max_j s2_j) is a global upper bound (lrelu monotone) -> no
// online rescaling. P computed directly in A-fragment lane order.
// MT=2 (32 rows, layer1: 4 waves = 2 mtiles x 2 feature-halves, each wave also
// produces the A-frag for kt = its feature-half index);
// MT=1 (16 rows, layer2: waves 0,1 produce kt=0,1; each wave owns one 16-f n-tile).
template<int FH, int MT>
__global__ __launch_bounds__(256) void attn_mfma_kernel(
    const __bf16* __restrict__ Htg,               // [heads*FH][NN] bf16 (transposed h)
    const unsigned long long* __restrict__ adj_bits,
    const float* __restrict__ s1_all, const float* __restrict__ s2_all,
    const float* __restrict__ s2max_all,
    float* __restrict__ outp, int ldo)
{
    constexpr int ROWS = MT * 16;
    constexpr int HSTR = 72;                      // padded LDS row stride (bf16): 2-way bank alias = free
    constexpr int NHW  = (MT == 2) ? 2 : 4;       // feature groups (one per consumer role)
    constexpr int NT   = FH / 16 / NHW;           // n-tiles per wave (layer1:4, layer2:1)
    const int head = blockIdx.y;
    const int row0 = blockIdx.x * ROWS;
    const int tid  = threadIdx.x;
    const int w    = tid >> 6;
    const int l    = tid & 63;
    const int o    = l >> 4;                      // k-octet
    const int rl   = l & 15;

    const bool prod = (MT == 2) ? true : (w < 2);
    const int  pmt  = (MT == 2) ? (w & 1) : 0;
    const int  pkt  = (MT == 2) ? (w >> 1) : w;   // kt this wave produces
    const int  cmt  = (MT == 2) ? (w & 1) : 0;
    const int  cnh  = (MT == 2) ? (w >> 1) : w;   // feature-group index

    __shared__ __attribute__((aligned(16))) __bf16 hlds[FH * HSTR];
    __shared__ __attribute__((aligned(16))) __bf16 plds[2 * MT * 64 * 8];  // [kt][mt][lane]*8
    __shared__ unsigned long long adjm[ROWS][65];
    __shared__ float lpart[2][ROWS];

    for (int i = tid; i < ROWS * 64; i += 256) {
        int r = i >> 6, c = i & 63;
        adjm[r][c] = adj_bits[(size_t)(row0 + r) * 64 + c];
    }

    const float* s1 = s1_all + (size_t)head * NN;
    const float* s2 = s2_all + (size_t)head * NN;
    const int prow = pmt * 16 + rl;
    const float s1r = s1[row0 + prow];
    float mrow;
    {
        float x = s1r + s2max_all[head];
        mrow = fmaxf(x, 0.2f * x);
    }
    float lacc = 0.f;
    bf16x8 myfrag;
    f32x4 acc[NT];
#pragma unroll
    for (int nt = 0; nt < NT; nt++) acc[nt] = (f32x4){0.f, 0.f, 0.f, 0.f};

    const __bf16* hg = Htg + (size_t)head * FH * NN;

    __syncthreads();   // adjm ready

    for (int jt = 0; jt < NN / 64; jt++) {
        // stage Ht tile: FH rows x 64 cols bf16 (16B chunks, coalesced)
        {
            constexpr int ITER = (FH * 8) / 256;
#pragma unroll
            for (int k = 0; k < ITER; k++) {
                int c = tid + k * 256;
                int f = c >> 3, seg = c & 7;
                f32x4 v = *(const f32x4*)(hg + (size_t)f * NN + jt * 64 + seg * 8);
                *(f32x4*)(&hlds[f * HSTR + seg * 8]) = v;
            }
        }
        // produce P in A-fragment order
        if (prod) {
            unsigned long long w64 = adjm[prow][jt];
            unsigned int mbyte = (unsigned int)(w64 >> ((pkt * 4 + o) * 8)) & 0xFFu;
            int jbase = jt * 64 + pkt * 32 + o * 8;
            f32x4 sa = *(const f32x4*)(s2 + jbase);
            f32x4 sb = *(const f32x4*)(s2 + jbase + 4);
            float pv[8]; float ps = 0.f;
#pragma unroll
            for (int q = 0; q < 8; q++) {
                float s2q = (q < 4) ? sa[q] : sb[q - 4];
                float x = s1r + s2q;
                float e = fmaxf(x, 0.2f * x);
                float p = ((mbyte >> q) & 1u) ? __expf(e - mrow) : 0.f;
                pv[q] = p; ps += p;
            }
#pragma unroll
            for (int q = 0; q < 8; q++) myfrag[q] = (__bf16)pv[q];
            *(bf16x8*)(&plds[((pkt * MT + pmt) * 64 + l) * 8]) = myfrag;
            ps += __shfl_xor(ps, 16, 64);
            ps += __shfl_xor(ps, 32, 64);
            lacc += ps;
        }
        __syncthreads();
        // consume: MFMA over both 32-k halves
#pragma unroll
        for (int kt = 0; kt < 2; kt++) {
            bf16x8 af;
            if (prod && kt == pkt && cmt == pmt) af = myfrag;
            else af = *(const bf16x8*)(&plds[((kt * MT + cmt) * 64 + l) * 8]);
#pragma unroll
            for (int nt = 0; nt < NT; nt++) {
                int f = cnh * (NT * 16) + nt * 16 + rl;
                bf16x8 bfr = *(const bf16x8*)(&hlds[f * HSTR + kt * 32 + o * 8]);
                acc[nt] = __builtin_amdgcn_mfma_f32_16x16x32_bf16(af, bfr, acc[nt], 0, 0, 0);
            }
        }
        __syncthreads();   // before next tile overwrites hlds/plds
    }
    if (prod && l < 16) lpart[pkt][pmt * 16 + l] = lacc;
    __syncthreads();
    // epilogue: normalize + elu + store (C layout: col=l&15, row=o*4+reg)
#pragma unroll
    for (int nt = 0; nt < NT; nt++) {
#pragma unroll
        for (int r4 = 0; r4 < 4; r4++) {
            int rloc = cmt * 16 + o * 4 + r4;
            float lr = lpart[0][rloc] + lpart[1][rloc];
            float inv = lr > 0.f ? 1.f / lr : 0.f;
            float v = acc[nt][r4] * inv;
            v = v > 0.f ? v : __expf(v) - 1.f;
            outp[(size_t)(row0 + rloc) * ldo + head * FH + cnh * (NT * 16) + nt * 16 + rl] = v;
        }
    }
}

// ---------------- row-wise log_softmax over 64 features ----------------
__global__ void logsoftmax_kernel(const float* __restrict__ in, float* __restrict__ out) {
    int gw = (blockIdx.x * blockDim.x + threadIdx.x) >> 6;
    int lane = threadIdx.x & 63;
    if (gw >= NN) return;
    float v = in[(size_t)gw * 64 + lane];
    float m = v;
#pragma unroll
    for (int off = 1; off < 64; off <<= 1) m = fmaxf(m, __shfl_xor(m, off, 64));
    float ex = __expf(v - m);
    float s = ex;
#pragma unroll
    for (int off = 1; off < 64; off <<= 1) s += __shfl_xor(s, off, 64);
    out[(size_t)gw * 64 + lane] = v - m - __logf(s);
}

extern "C" void kernel_launch(void* const* d_in, const int* in_sizes, int n_in,
                              void* d_out, int out_size, void* d_ws, size_t ws_size,
                              hipStream_t stream) {
    const float* X    = (const float*)d_in[0];
    const int*   adj  = (const int*)d_in[1];
    const float* W_h  = (const float*)d_in[2];
    const float* b_h  = (const float*)d_in[3];
    const float* a1_h = (const float*)d_in[4];
    const float* a2_h = (const float*)d_in[5];
    const float* ab_h = (const float*)d_in[6];
    const float* W_o  = (const float*)d_in[7];
    const float* b_o  = (const float*)d_in[8];
    const float* a1_o = (const float*)d_in[9];
    const float* a2_o = (const float*)d_in[10];
    const float* ab_o = (const float*)d_in[11];
    float* out = (float*)d_out;

    char* ws = (char*)d_ws;
    auto alloc = [&](size_t bytes) {
        char* p = ws; ws += (bytes + 255) & ~(size_t)255; return p;
    };
    unsigned long long* adj_bits = (unsigned long long*)alloc((size_t)NN * 64 * 8); // 2 MB
    float*  Bp     = (float*)alloc((size_t)512 * 512 * 4);   // 1 MB
    float*  biasp  = (float*)alloc(512 * 4);
    float*  h_all  = (float*)alloc((size_t)NN * 512 * 4);    // 8 MB
    float*  s1h    = (float*)alloc(4 * NN * 4);
    float*  s2h    = (float*)alloc(4 * NN * 4);
    float*  s2maxh = (float*)alloc(4 * 4);
    __bf16* Htg    = (__bf16*)alloc((size_t)512 * NN * 2);   // 4 MB
    float*  outh   = (float*)alloc((size_t)NN * 512 * 4);    // 8 MB
    float*  h2     = (float*)alloc((size_t)NN * 64 * 4);     // 1 MB
    float*  s1o    = (float*)alloc(NN * 4);
    float*  s2o    = (float*)alloc(NN * 4);
    float*  s2maxo = (float*)alloc(4);
    __bf16* Ht2    = (__bf16*)alloc((size_t)64 * NN * 2);    // 0.5 MB
    float*  out2   = (float*)alloc((size_t)NN * 64 * 4);     // 1 MB  (total ~26 MB)

    // 1. adjacency -> bitmasks
    pack_adj_kernel<<<(NN * 64) / 4, 256, 0, stream>>>(adj, adj_bits);
    // 2. prepack head weights
    prepack_kernel<<<1024, 256, 0, stream>>>(W_h, b_h, Bp, biasp);
    // 3. h_all[N,512] = X @ Bp + bias
    sgemm_bias_kernel<<<dim3(8, 64), 256, 0, stream>>>(X, Bp, biasp, h_all, NN, 512, 512);
    // 4. per-row logit halves
    s12_kernel<128><<<4096, 256, 0, stream>>>(h_all, 512, 4, a1_h, a2_h, ab_h, s1h, s2h);
    // 5. global s2 max per head
    smax_kernel<<<4, 256, 0, stream>>>(s2h, s2maxh);
    // 6. transpose h_all -> Htg bf16 [512][4096]
    transpose_cvt_kernel<<<dim3(16, 128), 256, 0, stream>>>(h_all, Htg, NN, 512);
    // 7. MFMA attention layer 1 (4 heads) -> outh[N,512]
    attn_mfma_kernel<128, 2><<<dim3(NN / 32, 4), 256, 0, stream>>>(
        Htg, adj_bits, s1h, s2h, s2maxh, outh, 512);
    // 8. output layer GEMM: h2[N,64] = outh @ W_o + b_o
    sgemm_bias_kernel<<<dim3(1, 64), 256, 0, stream>>>(outh, W_o, b_o, h2, NN, 64, 512);
    // 9. output layer logits
    s12_kernel<64><<<1024, 256, 0, stream>>>(h2, 64, 1, a1_o, a2_o, ab_o, s1o, s2o);
    // 10. s2 max (output layer)
    smax_kernel<<<1, 256, 0, stream>>>(s2o, s2maxo);
    // 11. transpose h2 -> Ht2 bf16 [64][4096]
    transpose_cvt_kernel<<<dim3(2, 128), 256, 0, stream>>>(h2, Ht2, NN, 64);
    // 12. MFMA attention layer 2 -> out2[N,64]
    attn_mfma_kernel<64, 1><<<dim3(NN / 16, 1), 256, 0, stream>>>(
        Ht2, adj_bits, s1o, s2o, s2maxo, out2, 64);
    // 13. log_softmax
    logsoftmax_kernel<<<1024, 256, 0, stream>>>(out2, out);
}

// Round 3
// 261.348 us; speedup vs baseline: 3.9897x; 1.3991x over previous
//
#include <hip/hip_runtime.h>
#include <math.h>

#define NN 4096   // nodes

using f32x4  = __attribute__((ext_vector_type(4))) float;
using bf16x4 = __attribute__((ext_vector_type(4))) __bf16;
using bf16x8 = __attribute__((ext_vector_type(8))) __bf16;

// ---------------- async global->LDS helpers (16B, swizzled) ----------------
// LDS tile layout: row f of 64 bf16 stored as 8 slots of 8; slot s holds global
// segment s ^ (f&7).  DMA dst for thread = uniform + lane*16 (HW requirement).
template<int FH>
__device__ __forceinline__ void stage_tile(const __bf16* __restrict__ hgp,
                                           __bf16* dst, int tid) {
#pragma unroll
    for (int it = 0; it < FH / 32; it++) {
        int c = tid + it * 256;
        int f = c >> 3, sl = c & 7;
        int g = sl ^ (f & 7);
        __builtin_amdgcn_global_load_lds(
            (const __attribute__((address_space(1))) void*)(hgp + (size_t)f * NN + g * 8),
            (__attribute__((address_space(3))) void*)(dst + (size_t)c * 8), 16, 0, 0);
    }
}

__device__ __forceinline__ void stage_g(const __bf16* __restrict__ base, int ldk,
                                        __bf16* dst, int tid) {
#pragma unroll
    for (int it = 0; it < 2; it++) {
        int c = tid + it * 256;
        int f = c >> 3, sl = c & 7;
        int g = sl ^ (f & 7);
        __builtin_amdgcn_global_load_lds(
            (const __attribute__((address_space(1))) void*)(base + (size_t)f * ldk + g * 8),
            (__attribute__((address_space(3))) void*)(dst + (size_t)c * 8), 16, 0, 0);
    }
}

// ---------------- adjacency -> bitmask ----------------
__global__ void pack_adj_kernel(const int* __restrict__ adj,
                                unsigned long long* __restrict__ bits) {
    int gw = (blockIdx.x * blockDim.x + threadIdx.x) >> 6;
    int lane = threadIdx.x & 63;
    int v = adj[(size_t)gw * 64 + lane];
    unsigned long long m = __ballot(v > 0);
    if (lane == 0) bits[gw] = m;
}

// ---------------- prepack: W_h -> Bt1[n=512][k=512] bf16, W_o -> Bt2[n=64][k=512] ----
__global__ void prepack_kernel(const float* __restrict__ W_h, const float* __restrict__ b_h,
                               const float* __restrict__ W_o,
                               __bf16* __restrict__ Bt1, float* __restrict__ biasp,
                               __bf16* __restrict__ Bt2) {
    int idx = blockIdx.x * 256 + threadIdx.x;   // 512*512
    {
        int n = idx >> 9, k = idx & 511;
        int h = n >> 7, f = n & 127;
        Bt1[idx] = (__bf16)W_h[(size_t)h * 512 * 128 + k * 128 + f];
    }
    if (idx < 64 * 512) {
        int n = idx >> 9, k = idx & 511;
        Bt2[idx] = (__bf16)W_o[k * 64 + n];
    }
    if (idx < 512) biasp[idx] = b_h[idx];
}

// ---------------- fp32 -> bf16 cast (4 elems/thread) ----------------
__global__ void cast_bf16_kernel(const float* __restrict__ src, __bf16* __restrict__ dst) {
    int i = blockIdx.x * 256 + threadIdx.x;
    f32x4 v = *(const f32x4*)(src + (size_t)i * 4);
    bf16x4 o;
#pragma unroll
    for (int q = 0; q < 4; q++) o[q] = (__bf16)v[q];
    *(bf16x4*)(dst + (size_t)i * 4) = o;
}

// ---------------- bf16 MFMA GEMM: C[M][N] = A[M][K] @ Bt[N][K]^T + bias ----------------
// BM=BN=BK=64, 4 waves (wave w = 16 m-rows), double-buffered DMA staging, 1 barrier/BK.
__global__ __launch_bounds__(256) void gemm_bt_kernel(
    const __bf16* __restrict__ A, const __bf16* __restrict__ Bt,
    const float* __restrict__ bias, float* __restrict__ C,
    int M, int N, int K)
{
    __shared__ __attribute__((aligned(16))) __bf16 As[2][64 * 64];
    __shared__ __attribute__((aligned(16))) __bf16 Bs[2][64 * 64];
    const int tid = threadIdx.x, w = tid >> 6, l = tid & 63, o = l >> 4, rl = l & 15;
    const int bm = blockIdx.y * 64, bn = blockIdx.x * 64;
    f32x4 acc[4] = {};
    stage_g(A + (size_t)bm * K, K, &As[0][0], tid);
    stage_g(Bt + (size_t)bn * K, K, &Bs[0][0], tid);
    const int KB = K / 64;
    for (int kb = 0; kb < KB; kb++) {
        int b = kb & 1;
        __syncthreads();
        if (kb + 1 < KB) {
            stage_g(A + (size_t)bm * K + (kb + 1) * 64, K, &As[b ^ 1][0], tid);
            stage_g(Bt + (size_t)bn * K + (kb + 1) * 64, K, &Bs[b ^ 1][0], tid);
        }
#pragma unroll
        for (int kt = 0; kt < 2; kt++) {
            int ra = w * 16 + rl;
            int cg = kt * 4 + o;
            bf16x8 af = *(const bf16x8*)(&As[b][(ra * 8 + (cg ^ (ra & 7))) * 8]);
#pragma unroll
            for (int nt = 0; nt < 4; nt++) {
                int rb = nt * 16 + rl;
                bf16x8 bfr = *(const bf16x8*)(&Bs[b][(rb * 8 + (cg ^ (rb & 7))) * 8]);
                acc[nt] = __builtin_amdgcn_mfma_f32_16x16x32_bf16(af, bfr, acc[nt], 0, 0, 0);
            }
        }
    }
#pragma unroll
    for (int nt = 0; nt < 4; nt++)
#pragma unroll
        for (int r4 = 0; r4 < 4; r4++) {
            int row = bm + w * 16 + o * 4 + r4;
            int col = bn + nt * 16 + rl;
            C[(size_t)row * N + col] = acc[nt][r4] + bias[col];
        }
}

// ---------------- per-row logits s1 = h@a1 + ab, s2 = h@a2 ----------------
template<int FH>
__global__ void s12_kernel(const float* __restrict__ hfeat, int ldh, int heads,
                           const float* __restrict__ a1, const float* __restrict__ a2,
                           const float* __restrict__ ab,
                           float* __restrict__ s1, float* __restrict__ s2)
{
    int gw = (blockIdx.x * blockDim.x + threadIdx.x) >> 6;
    int lane = threadIdx.x & 63;
    int row = gw / heads;
    int head = gw - row * heads;
    if (row >= NN) return;
    constexpr int E = FH / 64;
    const float* hr = hfeat + (size_t)row * ldh + head * FH;
    const float* a1h = a1 + head * FH;
    const float* a2h = a2 + head * FH;
    float p1 = 0.f, p2 = 0.f;
#pragma unroll
    for (int e = 0; e < E; e++) {
        float v = hr[lane * E + e];
        p1 += v * a1h[lane * E + e];
        p2 += v * a2h[lane * E + e];
    }
#pragma unroll
    for (int off = 1; off < 64; off <<= 1) {
        p1 += __shfl_xor(p1, off, 64);
        p2 += __shfl_xor(p2, off, 64);
    }
    if (lane == 0) {
        s1[head * NN + row] = p1 + ab[head];
        s2[head * NN + row] = p2;
    }
}

// ---------------- global max of s2 per head ----------------
__global__ void smax_kernel(const float* __restrict__ s2, float* __restrict__ s2max) {
    const float* p = s2 + (size_t)blockIdx.x * NN;
    int t = threadIdx.x;
    float m = -INFINITY;
    for (int i = t; i < NN; i += 256) m = fmaxf(m, p[i]);
#pragma unroll
    for (int off = 1; off < 64; off <<= 1) m = fmaxf(m, __shfl_xor(m, off, 64));
    __shared__ float red[4];
    if ((t & 63) == 0) red[t >> 6] = m;
    __syncthreads();
    if (t == 0) s2max[blockIdx.x] = fmaxf(fmaxf(red[0], red[1]), fmaxf(red[2], red[3]));
}

// ---------------- transpose + fp32->bf16: src[R][C] -> dst[C][R] ----------------
__global__ __launch_bounds__(256) void transpose_cvt_kernel(
    const float* __restrict__ src, __bf16* __restrict__ dst, int R, int C)
{
    __shared__ float tile[32][33];
    int tx = threadIdx.x & 31, ty = threadIdx.x >> 5;
    int c0 = blockIdx.x * 32, r0 = blockIdx.y * 32;
#pragma unroll
    for (int i = 0; i < 4; i++)
        tile[ty + 8 * i][tx] = src[(size_t)(r0 + ty + 8 * i) * C + c0 + tx];
    __syncthreads();
#pragma unroll
    for (int i = 0; i < 4; i++)
        dst[(size_t)(c0 + ty + 8 * i) * R + r0 + tx] = (__bf16)tile[tx][ty + 8 * i];
}

// ---------------- MFMA attention, j-split partials, 1 barrier per j-tile ----------------
// Writes UNNORMALIZED partial acc + partial row-sums l; combine kernels finish.
// m_i = lrelu(s1_i + max_j s2_j) is a global bound (lrelu monotone) -> partials
// from different j-splits add exactly.
template<int FH, int MT, int JSPLIT>
__global__ __launch_bounds__(256) void attn_part_kernel(
    const __bf16* __restrict__ Htg,               // [heads*FH][NN]
    const unsigned long long* __restrict__ adj_bits,
    const float* __restrict__ s1_all, const float* __restrict__ s2_all,
    const float* __restrict__ s2max_all,
    float* __restrict__ accp,                     // [JSPLIT][NN][ldo]
    float* __restrict__ lg,                       // [heads*JSPLIT][NN]
    int ldo)
{
    constexpr int ROWS = MT * 16;
    constexpr int NJT  = NN / 64 / JSPLIT;
    constexpr int NHW  = (MT == 2) ? 2 : 4;
    constexpr int NT   = FH / 16 / NHW;
    const int head = blockIdx.y;
    const int js   = blockIdx.z;
    const int row0 = blockIdx.x * ROWS;
    const int jt0  = js * NJT;
    const int tid = threadIdx.x;
    const int w = tid >> 6, l = tid & 63, o = l >> 4, rl = l & 15;

    const bool prod = (MT == 2) ? true : (w < 2);
    const int  pmt  = (MT == 2) ? (w & 1) : 0;
    const int  pkt  = (MT == 2) ? (w >> 1) : (w & 1);
    const int  cmt  = (MT == 2) ? (w & 1) : 0;
    const int  cnh  = (MT == 2) ? (w >> 1) : w;

    __shared__ __attribute__((aligned(16))) __bf16 hbuf[2][FH * 64];
    __shared__ __attribute__((aligned(16))) __bf16 plds[2][2 * MT * 64 * 8];
    __shared__ unsigned long long adjm[ROWS][NJT + 1];
    __shared__ float lpart[2][ROWS];

    const float* s1 = s1_all + (size_t)head * NN;
    const float* s2 = s2_all + (size_t)head * NN;
    const __bf16* hg = Htg + (size_t)head * FH * NN;
    const int prow = pmt * 16 + rl;
    const float s1r = s1[row0 + prow];
    float mrow; { float x = s1r + s2max_all[head]; mrow = fmaxf(x, 0.2f * x); }
    float lacc = 0.f;
    f32x4 acc[NT];
#pragma unroll
    for (int nt = 0; nt < NT; nt++) acc[nt] = (f32x4){0.f, 0.f, 0.f, 0.f};
    if (MT == 1 && tid < 2 * ROWS) lpart[tid >> 4][tid & 15] = 0.f;  // safety (all written anyway)

    // prologue: issue DMA for tile 0, stage adj masks
    stage_tile<FH>(hg + (size_t)jt0 * 64, &hbuf[0][0], tid);
    for (int i = tid; i < ROWS * NJT; i += 256) {
        int r = i / NJT, c = i - r * NJT;
        adjm[r][c] = adj_bits[(size_t)(row0 + r) * 64 + jt0 + c];
    }
    __syncthreads();   // adjm visible (also drains tile-0 DMA)

    auto produceP = [&](int jt, int b, bf16x8& frag) {
        unsigned long long w64 = adjm[prow][jt - jt0];
        unsigned int mbyte = (unsigned int)(w64 >> ((pkt * 4 + o) * 8)) & 0xFFu;
        int jb = jt * 64 + pkt * 32 + o * 8;
        f32x4 sa = *(const f32x4*)(s2 + jb);
        f32x4 sb = *(const f32x4*)(s2 + jb + 4);
        float ps = 0.f; float pv[8];
#pragma unroll
        for (int q = 0; q < 8; q++) {
            float s2q = (q < 4) ? sa[q] : sb[q - 4];
            float x = s1r + s2q;
            float e = fmaxf(x, 0.2f * x);
            float p = ((mbyte >> q) & 1u) ? __expf(e - mrow) : 0.f;
            pv[q] = p; ps += p;
        }
#pragma unroll
        for (int q = 0; q < 8; q++) frag[q] = (__bf16)pv[q];
        *(bf16x8*)(&plds[b][((pkt * MT + pmt) * 64 + l) * 8]) = frag;
        ps += __shfl_xor(ps, 16, 64);
        ps += __shfl_xor(ps, 32, 64);
        lacc += ps;
    };

    bf16x8 fcur = {}, fnext = {};
    if (prod) produceP(jt0, 0, fcur);

    for (int jl = 0; jl < NJT; jl++) {
        int b = jl & 1;
        __syncthreads();   // drains DMA(tile jl) + publishes plds[b]
        if (jl + 1 < NJT)
            stage_tile<FH>(hg + (size_t)(jt0 + jl + 1) * 64, &hbuf[b ^ 1][0], tid);
        // MFMA consume tile jl
#pragma unroll
        for (int kt = 0; kt < 2; kt++) {
            bf16x8 af;
            if (prod && kt == pkt) af = fcur;
            else af = *(const bf16x8*)(&plds[b][((kt * MT + cmt) * 64 + l) * 8]);
#pragma unroll
            for (int nt = 0; nt < NT; nt++) {
                int f = cnh * (NT * 16) + nt * 16 + rl;
                int slot = (kt * 4 + o) ^ (f & 7);
                bf16x8 bfr = *(const bf16x8*)(&hbuf[b][(f * 8 + slot) * 8]);
                acc[nt] = __builtin_amdgcn_mfma_f32_16x16x32_bf16(af, bfr, acc[nt], 0, 0, 0);
            }
        }
        if (prod && jl + 1 < NJT) {
            produceP(jt0 + jl + 1, b ^ 1, fnext);
            fcur = fnext;
        }
    }

    if (prod && l < 16) lpart[pkt][prow] = lacc;
    __syncthreads();
#pragma unroll
    for (int nt = 0; nt < NT; nt++)
#pragma unroll
        for (int r4 = 0; r4 < 4; r4++) {
            int rloc = cmt * 16 + o * 4 + r4;
            accp[((size_t)js * NN + row0 + rloc) * ldo + head * FH + cnh * (NT * 16) + nt * 16 + rl]
                = acc[nt][r4];
        }
    if (tid < ROWS)
        lg[((size_t)head * JSPLIT + js) * NN + row0 + tid] = lpart[0][tid] + lpart[1][tid];
}

// ---------------- combine layer-1 partials: normalize + elu -> bf16 [N][512] ----------------
__global__ void combine1_kernel(const float* __restrict__ accp, const float* __restrict__ lg,
                                __bf16* __restrict__ outb) {
    int gid = blockIdx.x * 256 + threadIdx.x;        // N * 128
    int row = gid >> 7, c4 = (gid & 127) * 4;
    int head = c4 >> 7;
    float lsum = 0.f;
#pragma unroll
    for (int js = 0; js < 4; js++) lsum += lg[((size_t)head * 4 + js) * NN + row];
    float inv = lsum > 0.f ? 1.f / lsum : 0.f;
    f32x4 v = {};
#pragma unroll
    for (int js = 0; js < 4; js++)
        v += *(const f32x4*)(accp + ((size_t)js * NN + row) * 512 + c4);
    bf16x4 ob;
#pragma unroll
    for (int q = 0; q < 4; q++) {
        float x = v[q] * inv;
        x = x > 0.f ? x : __expf(x) - 1.f;
        ob[q] = (__bf16)x;
    }
    *(bf16x4*)(outb + (size_t)row * 512 + c4) = ob;
}

// ---------------- combine layer-2 partials + elu + log_softmax -> out ----------------
__global__ void combine2_kernel(const float* __restrict__ accp, const float* __restrict__ lg,
                                float* __restrict__ out) {
    int row = (blockIdx.x * 256 + threadIdx.x) >> 6;
    int lane = threadIdx.x & 63;
    if (row >= NN) return;
    float lsum = 0.f, v = 0.f;
#pragma unroll
    for (int js = 0; js < 8; js++) {
        lsum += lg[(size_t)js * NN + row];
        v += accp[((size_t)js * NN + row) * 64 + lane];
    }
    float inv = lsum > 0.f ? 1.f / lsum : 0.f;
    v *= inv;
    v = v > 0.f ? v : __expf(v) - 1.f;
    float m = v;
#pragma unroll
    for (int off = 1; off < 64; off <<= 1) m = fmaxf(m, __shfl_xor(m, off, 64));
    float ex = __expf(v - m);
    float s = ex;
#pragma unroll
    for (int off = 1; off < 64; off <<= 1) s += __shfl_xor(s, off, 64);
    out[(size_t)row * 64 + lane] = v - m - __logf(s);
}

extern "C" void kernel_launch(void* const* d_in, const int* in_sizes, int n_in,
                              void* d_out, int out_size, void* d_ws, size_t ws_size,
                              hipStream_t stream) {
    const float* X    = (const float*)d_in[0];
    const int*   adj  = (const int*)d_in[1];
    const float* W_h  = (const float*)d_in[2];
    const float* b_h  = (const float*)d_in[3];
    const float* a1_h = (const float*)d_in[4];
    const float* a2_h = (const float*)d_in[5];
    const float* ab_h = (const float*)d_in[6];
    const float* W_o  = (const float*)d_in[7];
    const float* b_o  = (const float*)d_in[8];
    const float* a1_o = (const float*)d_in[9];
    const float* a2_o = (const float*)d_in[10];
    const float* ab_o = (const float*)d_in[11];
    float* out = (float*)d_out;

    char* ws = (char*)d_ws;
    auto alloc = [&](size_t bytes) {
        char* p = ws; ws += (bytes + 255) & ~(size_t)255; return p;
    };
    unsigned long long* adj_bits = (unsigned long long*)alloc((size_t)NN * 64 * 8); // 2 MB
    __bf16* Bt1    = (__bf16*)alloc((size_t)512 * 512 * 2);  // 512 KB
    float*  biasp  = (float*)alloc(512 * 4);
    __bf16* Bt2    = (__bf16*)alloc((size_t)64 * 512 * 2);   // 64 KB
    __bf16* Xb     = (__bf16*)alloc((size_t)NN * 512 * 2);   // 4 MB
    float*  h_all  = (float*)alloc((size_t)NN * 512 * 4);    // 8 MB
    float*  s1h    = (float*)alloc(4 * NN * 4);
    float*  s2h    = (float*)alloc(4 * NN * 4);
    float*  s2maxh = (float*)alloc(4 * 4);
    __bf16* Htg    = (__bf16*)alloc((size_t)512 * NN * 2);   // 4 MB
    float*  accp1  = (float*)alloc((size_t)4 * NN * 512 * 4); // 32 MB
    float*  lg1    = (float*)alloc((size_t)16 * NN * 4);
    __bf16* outhb  = (__bf16*)alloc((size_t)NN * 512 * 2);   // 4 MB
    float*  h2     = (float*)alloc((size_t)NN * 64 * 4);     // 1 MB
    float*  s1o    = (float*)alloc(NN * 4);
    float*  s2o    = (float*)alloc(NN * 4);
    float*  s2maxo = (float*)alloc(4);
    __bf16* Ht2    = (__bf16*)alloc((size_t)64 * NN * 2);    // 512 KB
    float*  accp2  = (float*)alloc((size_t)8 * NN * 64 * 4); // 8 MB
    float*  lg2    = (float*)alloc((size_t)8 * NN * 4);      // total ~65 MB

    // 1. adjacency -> bitmasks
    pack_adj_kernel<<<(NN * 64) / 4, 256, 0, stream>>>(adj, adj_bits);
    // 2. prepack weights (bf16, [n][k])
    prepack_kernel<<<1024, 256, 0, stream>>>(W_h, b_h, W_o, Bt1, biasp, Bt2);
    // 3. X -> bf16
    cast_bf16_kernel<<<(NN * 512 / 4) / 256, 256, 0, stream>>>(X, Xb);
    // 4. h_all[N,512] = Xb @ Bt1^T + bias   (bf16 MFMA)
    gemm_bt_kernel<<<dim3(8, 64), 256, 0, stream>>>(Xb, Bt1, biasp, h_all, NN, 512, 512);
    // 5. per-row logit halves, 4 heads
    s12_kernel<128><<<4096, 256, 0, stream>>>(h_all, 512, 4, a1_h, a2_h, ab_h, s1h, s2h);
    // 6. global s2 max per head
    smax_kernel<<<4, 256, 0, stream>>>(s2h, s2maxh);
    // 7. transpose h_all -> Htg bf16 [512][4096]
    transpose_cvt_kernel<<<dim3(16, 128), 256, 0, stream>>>(h_all, Htg, NN, 512);
    // 8. attention layer 1 partials (4 heads x 4 j-splits)
    attn_part_kernel<128, 2, 4><<<dim3(NN / 32, 4, 4), 256, 0, stream>>>(
        Htg, adj_bits, s1h, s2h, s2maxh, accp1, lg1, 512);
    // 9. combine -> elu -> bf16 concat features [N][512]
    combine1_kernel<<<(NN * 128) / 256, 256, 0, stream>>>(accp1, lg1, outhb);
    // 10. h2[N,64] = outhb @ Bt2^T + b_o
    gemm_bt_kernel<<<dim3(1, 64), 256, 0, stream>>>(outhb, Bt2, b_o, h2, NN, 64, 512);
    // 11. output layer logits
    s12_kernel<64><<<1024, 256, 0, stream>>>(h2, 64, 1, a1_o, a2_o, ab_o, s1o, s2o);
    // 12. s2 max (output layer)
    smax_kernel<<<1, 256, 0, stream>>>(s2o, s2maxo);
    // 13. transpose h2 -> Ht2 bf16 [64][4096]
    transpose_cvt_kernel<<<dim3(2, 128), 256, 0, stream>>>(h2, Ht2, NN, 64);
    // 14. attention layer 2 partials (8 j-splits)
    attn_part_kernel<64, 1, 8><<<dim3(NN / 16, 1, 8), 256, 0, stream>>>(
        Ht2, adj_bits, s1o, s2o, s2maxo, accp2, lg2, 64);
    // 15. combine + elu + log_softmax -> out
    combine2_kernel<<<(NN * 64) / 256, 256, 0, stream>>>(accp2, lg2, out);
}

// Round 4
// 232.310 us; speedup vs baseline: 4.4884x; 1.1250x over previous
//
#include <hip/hip_runtime.h>
#include <math.h>

#define NN 4096   // nodes

using f32x4  = __attribute__((ext_vector_type(4))) float;
using bf16x4 = __attribute__((ext_vector_type(4))) __bf16;
using bf16x8 = __attribute__((ext_vector_type(8))) __bf16;

// lgkm-only barrier: does NOT drain vmcnt, so global_load_lds prefetch stays in
// flight across it (plain __syncthreads would emit s_waitcnt vmcnt(0)).
__device__ __forceinline__ void barrier_lgkm() {
    asm volatile("s_waitcnt lgkmcnt(0)\ns_barrier" ::: "memory");
}

// ---------------- async global->LDS staging (16B, XOR-swizzled chunks) ----------------
// Row f of 64 bf16 = 8 chunks of 8; LDS slot s of row f holds global chunk s^(f&7).
template<int FH>
__device__ __forceinline__ void stage_tile(const __bf16* __restrict__ hgp,
                                           __bf16* dst, int tid) {
#pragma unroll
    for (int it = 0; it < FH / 32; it++) {
        int c = tid + it * 256;
        int f = c >> 3, sl = c & 7;
        int g = sl ^ (f & 7);
        __builtin_amdgcn_global_load_lds(
            (const __attribute__((address_space(1))) void*)(hgp + (size_t)f * NN + g * 8),
            (__attribute__((address_space(3))) void*)(dst + (size_t)c * 8), 16, 0, 0);
    }
}

__device__ __forceinline__ void stage_g(const __bf16* __restrict__ base, int ldk,
                                        __bf16* dst, int tid) {
#pragma unroll
    for (int it = 0; it < 2; it++) {
        int c = tid + it * 256;
        int f = c >> 3, sl = c & 7;
        int g = sl ^ (f & 7);
        __builtin_amdgcn_global_load_lds(
            (const __attribute__((address_space(1))) void*)(base + (size_t)f * ldk + g * 8),
            (__attribute__((address_space(3))) void*)(dst + (size_t)c * 8), 16, 0, 0);
    }
}

// ---------------- adjacency -> bitmask ----------------
__global__ void pack_adj_kernel(const int* __restrict__ adj,
                                unsigned long long* __restrict__ bits) {
    int gw = (blockIdx.x * blockDim.x + threadIdx.x) >> 6;
    int lane = threadIdx.x & 63;
    int v = adj[(size_t)gw * 64 + lane];
    unsigned long long m = __ballot(v > 0);
    if (lane == 0) bits[gw] = m;
}

// ---------------- prepack: W_h -> Bt1[n=512][k=512] bf16, W_o -> Bt2[n=64][k=512] ----
__global__ void prepack_kernel(const float* __restrict__ W_h, const float* __restrict__ b_h,
                               const float* __restrict__ W_o,
                               __bf16* __restrict__ Bt1, float* __restrict__ biasp,
                               __bf16* __restrict__ Bt2) {
    int idx = blockIdx.x * 256 + threadIdx.x;   // 512*512
    {
        int n = idx >> 9, k = idx & 511;
        int h = n >> 7, f = n & 127;
        Bt1[idx] = (__bf16)W_h[(size_t)h * 512 * 128 + k * 128 + f];
    }
    if (idx < 64 * 512) {
        int n = idx >> 9, k = idx & 511;
        Bt2[idx] = (__bf16)W_o[k * 64 + n];
    }
    if (idx < 512) biasp[idx] = b_h[idx];
}

// ---------------- fp32 -> bf16 cast ----------------
__global__ void cast_bf16_kernel(const float* __restrict__ src, __bf16* __restrict__ dst) {
    int i = blockIdx.x * 256 + threadIdx.x;
    f32x4 v = *(const f32x4*)(src + (size_t)i * 4);
    bf16x4 o;
#pragma unroll
    for (int q = 0; q < 4; q++) o[q] = (__bf16)v[q];
    *(bf16x4*)(dst + (size_t)i * 4) = o;
}

// ---------------- fused bf16 MFMA GEMM ----------------
// Ht[col][row] = bf16( (A @ Bt^T)[row][col] + bias[col] )   (transposed store)
// s1[head][row] += sum_col h*a1[col], s2 likewise (fp32 atomics; head = bn>>7)
__global__ __launch_bounds__(256) void gemm_fused_kernel(
    const __bf16* __restrict__ A, const __bf16* __restrict__ Bt,
    const float* __restrict__ bias,
    const float* __restrict__ a1, const float* __restrict__ a2,
    __bf16* __restrict__ Ht, float* __restrict__ s1, float* __restrict__ s2,
    int M, int N, int K)
{
    __shared__ __attribute__((aligned(16))) __bf16 As[2][64 * 64];
    __shared__ __attribute__((aligned(16))) __bf16 Bs[2][64 * 64];
    const int tid = threadIdx.x, w = tid >> 6, l = tid & 63, o = l >> 4, rl = l & 15;
    const int bm = blockIdx.y * 64, bn = blockIdx.x * 64;
    f32x4 acc[4] = {};
    stage_g(A + (size_t)bm * K, K, &As[0][0], tid);
    stage_g(Bt + (size_t)bn * K, K, &Bs[0][0], tid);
    const int KB = K / 64;
    for (int kb = 0; kb < KB; kb++) {
        int b = kb & 1;
        __syncthreads();
        if (kb + 1 < KB) {
            stage_g(A + (size_t)bm * K + (kb + 1) * 64, K, &As[b ^ 1][0], tid);
            stage_g(Bt + (size_t)bn * K + (kb + 1) * 64, K, &Bs[b ^ 1][0], tid);
        }
#pragma unroll
        for (int kt = 0; kt < 2; kt++) {
            int ra = w * 16 + rl;
            int cg = kt * 4 + o;
            bf16x8 af = *(const bf16x8*)(&As[b][(ra * 8 + (cg ^ (ra & 7))) * 8]);
#pragma unroll
            for (int nt = 0; nt < 4; nt++) {
                int rb = nt * 16 + rl;
                bf16x8 bfr = *(const bf16x8*)(&Bs[b][(rb * 8 + (cg ^ (rb & 7))) * 8]);
                acc[nt] = __builtin_amdgcn_mfma_f32_16x16x32_bf16(af, bfr, acc[nt], 0, 0, 0);
            }
        }
    }
    // epilogue: bias, transposed bf16 store, s1/s2 row-dot partials
    const int head = bn >> 7;
    const int row_base = bm + w * 16 + o * 4;
    float p1[4] = {0.f, 0.f, 0.f, 0.f}, p2[4] = {0.f, 0.f, 0.f, 0.f};
#pragma unroll
    for (int nt = 0; nt < 4; nt++) {
        int col = bn + nt * 16 + rl;
        float bv = bias[col];
        float a1v = a1[col], a2v = a2[col];
        bf16x4 hv;
#pragma unroll
        for (int r4 = 0; r4 < 4; r4++) {
            float h = acc[nt][r4] + bv;
            hv[r4] = (__bf16)h;
            p1[r4] += h * a1v;
            p2[r4] += h * a2v;
        }
        *(bf16x4*)(Ht + (size_t)col * M + row_base) = hv;
    }
#pragma unroll
    for (int r4 = 0; r4 < 4; r4++)
#pragma unroll
        for (int off = 1; off < 16; off <<= 1) {
            p1[r4] += __shfl_xor(p1[r4], off, 64);
            p2[r4] += __shfl_xor(p2[r4], off, 64);
        }
    if (rl == 0)
#pragma unroll
        for (int r4 = 0; r4 < 4; r4++) {
            atomicAdd(&s1[(size_t)head * M + row_base + r4], p1[r4]);
            atomicAdd(&s2[(size_t)head * M + row_base + r4], p2[r4]);
        }
}

// ---------------- global max of s2 per head ----------------
__global__ void smax_kernel(const float* __restrict__ s2, float* __restrict__ s2max) {
    const float* p = s2 + (size_t)blockIdx.x * NN;
    int t = threadIdx.x;
    float m = -INFINITY;
    for (int i = t; i < NN; i += 256) m = fmaxf(m, p[i]);
#pragma unroll
    for (int off = 1; off < 64; off <<= 1) m = fmaxf(m, __shfl_xor(m, off, 64));
    __shared__ float red[4];
    if ((t & 63) == 0) red[t >> 6] = m;
    __syncthreads();
    if (t == 0) s2max[blockIdx.x] = fmaxf(fmaxf(red[0], red[1]), fmaxf(red[2], red[3]));
}

// ---------------- MFMA attention, fragment-reuse, j-split partials ----------------
// 64-row blocks, 4 waves. Wave w produces P A-frags for rows [w*16, w*16+16)
// (kept in regs + published once to plds) and consumes n-tiles
// [w*NTW*16, (w+1)*NTW*16) for ALL 4 m-tiles (A/B-frag reuse: 10 LDS reads
// per 16 MFMA at FH=128). Single plds buffer; B2 = lgkm-only barrier so the
// hbuf DMA prefetch survives. m = lrelu(s1+max s2) is a global softmax bound
// (lrelu monotone) -> j-split partials add exactly; combine kernels finish.
template<int FH, int JSPLIT>
__global__ __launch_bounds__(256, 4) void attn_kernel(
    const __bf16* __restrict__ Htg,               // [heads*FH][NN]
    const unsigned long long* __restrict__ adj_bits,
    const float* __restrict__ s1_all, const float* __restrict__ s2_all,
    const float* __restrict__ s2max_all, const float* __restrict__ ab_all,
    __bf16* __restrict__ accp,                    // [JSPLIT][NN][ldo]
    float* __restrict__ lg,                       // [heads*JSPLIT][NN]
    int ldo)
{
    constexpr int NJT = NN / 64 / JSPLIT;
    constexpr int NTW = FH / 64;                  // n-tiles per wave (128->2, 64->1)
    const int head = blockIdx.y;
    const int js   = blockIdx.z;
    const int row0 = blockIdx.x * 64;
    const int jt0  = js * NJT;
    const int tid = threadIdx.x;
    const int w = tid >> 6, l = tid & 63, o = l >> 4, rl = l & 15;
    const int myrow = row0 + w * 16 + rl;         // producer row (mt = w)

    __shared__ __attribute__((aligned(16))) __bf16 hbuf[2][FH * 64];
    __shared__ __attribute__((aligned(16))) __bf16 plds[8 * 64 * 8];   // [mt*2+kt][lane]*8

    const float* s2 = s2_all + (size_t)head * NN;
    const __bf16* hg = Htg + (size_t)head * FH * NN;
    const float s1r = s1_all[(size_t)head * NN + myrow] + ab_all[head];
    float mrow; { float x = s1r + s2max_all[head]; mrow = fmaxf(x, 0.2f * x); }
    float lacc = 0.f;
    f32x4 acc[4][NTW] = {};

    stage_tile<FH>(hg + (size_t)jt0 * 64, &hbuf[0][0], tid);

    for (int jl = 0; jl < NJT; jl++) {
        const int b = jl & 1;
        const int jt = jt0 + jl;
        // ---- produce A-frags for rows mt=w ----
        unsigned long long aw = adj_bits[(size_t)myrow * 64 + jt];
        bf16x8 freg[2];
#pragma unroll
        for (int kt = 0; kt < 2; kt++) {
            unsigned int mbyte = (unsigned int)(aw >> ((kt * 4 + o) * 8)) & 0xFFu;
            int jb = jt * 64 + kt * 32 + o * 8;
            f32x4 sa = *(const f32x4*)(s2 + jb);
            f32x4 sb = *(const f32x4*)(s2 + jb + 4);
            float ps = 0.f;
#pragma unroll
            for (int q = 0; q < 8; q++) {
                float s2q = (q < 4) ? sa[q] : sb[q - 4];
                float x = s1r + s2q;
                float e = fmaxf(x, 0.2f * x);
                float p = ((mbyte >> q) & 1u) ? __expf(e - mrow) : 0.f;
                freg[kt][q] = (__bf16)p;
                ps += p;
            }
            ps += __shfl_xor(ps, 16, 64);
            ps += __shfl_xor(ps, 32, 64);
            lacc += ps;
            *(bf16x8*)(&plds[((w * 2 + kt) * 64 + l) * 8]) = freg[kt];
        }
        __syncthreads();   // B1: plds visible; hbuf[b] DMA drained (vmcnt 0)
        if (jl + 1 < NJT)
            stage_tile<FH>(hg + (size_t)(jt + 1) * 64, &hbuf[b ^ 1][0], tid);
        // ---- consume: B-frags once, reuse across all 4 m-tiles ----
        bf16x8 bfr[2][NTW];
#pragma unroll
        for (int kt = 0; kt < 2; kt++)
#pragma unroll
            for (int ntl = 0; ntl < NTW; ntl++) {
                int f = (w * NTW + ntl) * 16 + rl;
                int slot = (kt * 4 + o) ^ (rl & 7);
                bfr[kt][ntl] = *(const bf16x8*)(&hbuf[b][(f * 8 + slot) * 8]);
            }
#pragma unroll
        for (int mt = 0; mt < 4; mt++)
#pragma unroll
            for (int kt = 0; kt < 2; kt++) {
                bf16x8 af = (mt == w) ? freg[kt]
                          : *(const bf16x8*)(&plds[((mt * 2 + kt) * 64 + l) * 8]);
#pragma unroll
                for (int ntl = 0; ntl < NTW; ntl++)
                    acc[mt][ntl] = __builtin_amdgcn_mfma_f32_16x16x32_bf16(
                        af, bfr[kt][ntl], acc[mt][ntl], 0, 0, 0);
            }
        barrier_lgkm();    // B2: plds reads done; DMA prefetch stays in flight
    }
    // ---- epilogue: partial row-sums + unnormalized bf16 partial acc ----
    if (l < 16) lg[((size_t)head * JSPLIT + js) * NN + row0 + w * 16 + l] = lacc;
#pragma unroll
    for (int mt = 0; mt < 4; mt++)
#pragma unroll
        for (int ntl = 0; ntl < NTW; ntl++)
#pragma unroll
            for (int r4 = 0; r4 < 4; r4++) {
                int grow = row0 + mt * 16 + o * 4 + r4;
                int gcol = head * FH + (w * NTW + ntl) * 16 + rl;
                accp[((size_t)js * NN + grow) * ldo + gcol] = (__bf16)acc[mt][ntl][r4];
            }
}

// ---------------- combine layer-1 partials: normalize + elu -> bf16 [N][512] ----------------
__global__ void combine1_kernel(const __bf16* __restrict__ accp, const float* __restrict__ lg,
                                __bf16* __restrict__ outb) {
    int gid = blockIdx.x * 256 + threadIdx.x;        // N * 128
    int row = gid >> 7, c4 = (gid & 127) * 4;
    int head = c4 >> 7;
    float lsum = 0.f;
#pragma unroll
    for (int js = 0; js < 4; js++) lsum += lg[((size_t)head * 4 + js) * NN + row];
    float inv = lsum > 0.f ? 1.f / lsum : 0.f;
    float v[4] = {0.f, 0.f, 0.f, 0.f};
#pragma unroll
    for (int js = 0; js < 4; js++) {
        bf16x4 t = *(const bf16x4*)(accp + ((size_t)js * NN + row) * 512 + c4);
#pragma unroll
        for (int q = 0; q < 4; q++) v[q] += (float)t[q];
    }
    bf16x4 ob;
#pragma unroll
    for (int q = 0; q < 4; q++) {
        float x = v[q] * inv;
        x = x > 0.f ? x : __expf(x) - 1.f;
        ob[q] = (__bf16)x;
    }
    *(bf16x4*)(outb + (size_t)row * 512 + c4) = ob;
}

// ---------------- combine layer-2 partials + elu + log_softmax -> out ----------------
__global__ void combine2_kernel(const __bf16* __restrict__ accp, const float* __restrict__ lg,
                                float* __restrict__ out) {
    int row = (blockIdx.x * 256 + threadIdx.x) >> 6;
    int lane = threadIdx.x & 63;
    if (row >= NN) return;
    float lsum = 0.f, v = 0.f;
#pragma unroll
    for (int js = 0; js < 16; js++) {
        lsum += lg[(size_t)js * NN + row];
        v += (float)accp[((size_t)js * NN + row) * 64 + lane];
    }
    float inv = lsum > 0.f ? 1.f / lsum : 0.f;
    v *= inv;
    v = v > 0.f ? v : __expf(v) - 1.f;
    float m = v;
#pragma unroll
    for (int off = 1; off < 64; off <<= 1) m = fmaxf(m, __shfl_xor(m, off, 64));
    float ex = __expf(v - m);
    float s = ex;
#pragma unroll
    for (int off = 1; off < 64; off <<= 1) s += __shfl_xor(s, off, 64);
    out[(size_t)row * 64 + lane] = v - m - __logf(s);
}

extern "C" void kernel_launch(void* const* d_in, const int* in_sizes, int n_in,
                              void* d_out, int out_size, void* d_ws, size_t ws_size,
                              hipStream_t stream) {
    const float* X    = (const float*)d_in[0];
    const int*   adj  = (const int*)d_in[1];
    const float* W_h  = (const float*)d_in[2];
    const float* b_h  = (const float*)d_in[3];
    const float* a1_h = (const float*)d_in[4];
    const float* a2_h = (const float*)d_in[5];
    const float* ab_h = (const float*)d_in[6];
    const float* W_o  = (const float*)d_in[7];
    const float* b_o  = (const float*)d_in[8];
    const float* a1_o = (const float*)d_in[9];
    const float* a2_o = (const float*)d_in[10];
    const float* ab_o = (const float*)d_in[11];
    float* out = (float*)d_out;

    char* ws = (char*)d_ws;
    auto alloc = [&](size_t bytes) {
        char* p = ws; ws += (bytes + 255) & ~(size_t)255; return p;
    };
    unsigned long long* adj_bits = (unsigned long long*)alloc((size_t)NN * 64 * 8); // 2 MB
    __bf16* Bt1    = (__bf16*)alloc((size_t)512 * 512 * 2);     // 512 KB
    float*  biasp  = (float*)alloc(512 * 4);
    __bf16* Bt2    = (__bf16*)alloc((size_t)64 * 512 * 2);      // 64 KB
    __bf16* Xb     = (__bf16*)alloc((size_t)NN * 512 * 2);      // 4 MB
    float*  s1h    = (float*)alloc((size_t)4 * NN * 4);         // |-- contiguous,
    float*  s2h    = (float*)alloc((size_t)4 * NN * 4);         // |   one memset
    float*  s1o    = (float*)alloc((size_t)NN * 4);             // |   (160 KB)
    float*  s2o    = (float*)alloc((size_t)NN * 4);             // |
    float*  s2maxh = (float*)alloc(4 * 4);
    float*  s2maxo = (float*)alloc(4);
    __bf16* Htg    = (__bf16*)alloc((size_t)512 * NN * 2);      // 4 MB
    __bf16* accp1  = (__bf16*)alloc((size_t)4 * NN * 512 * 2);  // 16 MB
    float*  lg1    = (float*)alloc((size_t)16 * NN * 4);        // 256 KB
    __bf16* outhb  = (__bf16*)alloc((size_t)NN * 512 * 2);      // 4 MB
    __bf16* Ht2    = (__bf16*)alloc((size_t)64 * NN * 2);       // 512 KB
    __bf16* accp2  = (__bf16*)alloc((size_t)16 * NN * 64 * 2);  // 8 MB
    float*  lg2    = (float*)alloc((size_t)16 * NN * 4);        // 256 KB  (~40 MB)

    // 0. zero the atomic s1/s2 accumulators (contiguous block)
    hipMemsetAsync(s1h, 0, (size_t)(4 + 4 + 1 + 1) * NN * 4, stream);
    // 1. adjacency -> bitmasks (single read of the 67 MB int32 matrix)
    pack_adj_kernel<<<(NN * 64) / 4, 256, 0, stream>>>(adj, adj_bits);
    // 2. prepack weights (bf16, [n][k])
    prepack_kernel<<<1024, 256, 0, stream>>>(W_h, b_h, W_o, Bt1, biasp, Bt2);
    // 3. X -> bf16
    cast_bf16_kernel<<<(NN * 512 / 4) / 256, 256, 0, stream>>>(X, Xb);
    // 4. layer-1 GEMM fused: Htg (transposed bf16) + s1h/s2h atomics
    gemm_fused_kernel<<<dim3(8, 64), 256, 0, stream>>>(
        Xb, Bt1, biasp, a1_h, a2_h, Htg, s1h, s2h, NN, 512, 512);
    // 5. per-head global s2 max
    smax_kernel<<<4, 256, 0, stream>>>(s2h, s2maxh);
    // 6. attention layer 1 partials (4 heads x 4 j-splits)
    attn_kernel<128, 4><<<dim3(NN / 64, 4, 4), 256, 0, stream>>>(
        Htg, adj_bits, s1h, s2h, s2maxh, ab_h, accp1, lg1, 512);
    // 7. combine -> elu -> bf16 concat features [N][512]
    combine1_kernel<<<(NN * 128) / 256, 256, 0, stream>>>(accp1, lg1, outhb);
    // 8. layer-2 GEMM fused: Ht2 (transposed bf16) + s1o/s2o atomics
    gemm_fused_kernel<<<dim3(1, 64), 256, 0, stream>>>(
        outhb, Bt2, b_o, a1_o, a2_o, Ht2, s1o, s2o, NN, 64, 512);
    // 9. s2 max (output layer)
    smax_kernel<<<1, 256, 0, stream>>>(s2o, s2maxo);
    // 10. attention layer 2 partials (16 j-splits)
    attn_kernel<64, 16><<<dim3(NN / 64, 1, 16), 256, 0, stream>>>(
        Ht2, adj_bits, s1o, s2o, s2maxo, ab_o, accp2, lg2, 64);
    // 11. combine + elu + log_softmax -> out
    combine2_kernel<<<(NN * 64) / 256, 256, 0, stream>>>(accp2, lg2, out);
}